// Round 5
// baseline (196.230 us; speedup 1.0000x reference)
//
#include <hip/hip_runtime.h>

// ---------------- types / helpers ----------------
typedef __attribute__((ext_vector_type(4))) float f32x4;
typedef __attribute__((ext_vector_type(8))) __bf16 bf16x8;
typedef __attribute__((ext_vector_type(8))) unsigned short u16x8;

__device__ __forceinline__ unsigned short f2bf(float f) {
    unsigned int u = __float_as_uint(f);
    u += 0x7fffu + ((u >> 16) & 1u);       // RTNE
    return (unsigned short)(u >> 16);
}

__device__ __forceinline__ float softplus_f(float x) {
    float e = __expf(-fabsf(x));
    return fmaxf(x, 0.0f) + __logf(1.0f + e);
}

typedef __attribute__((address_space(3))) void lds_void_t;
typedef __attribute__((address_space(1))) void glb_void_t;

__device__ __forceinline__ void load16_to_lds(const void* g, const void* l) {
    __builtin_amdgcn_global_load_lds((glb_void_t*)(unsigned long long)g,
                                     (lds_void_t*)(unsigned int)(unsigned long long)l,
                                     16, 0, 0);
}

// ---------------- repack: bf16 A=[x|iv|temb] then W=[Wa|Wi|Wt], dst contiguous ----------------
#define REPACK_NB 4
#define REPACK_BLOCKS 864
__global__ __launch_bounds__(256) void repack(
        const float* __restrict__ x, const float* __restrict__ iv,
        const float* __restrict__ temb,
        const float* __restrict__ Wa, const float* __restrict__ Wi,
        const float* __restrict__ Wt,
        unsigned short* __restrict__ Abf /* Wbf follows contiguously */) {
    const int stride = REPACK_BLOCKS * 256;
    const int tid0 = blockIdx.x * 256 + threadIdx.x;
    float4 f[REPACK_NB][2];
    #pragma unroll
    for (int c = 0; c < REPACK_NB; ++c) {
        const int idx = tid0 + c * stride;
        const bool isA = idx < 98304;
        const int widx = isA ? idx : idx - 98304;
        const int row = widx / 48;
        const int kk  = (widx % 48) * 8;
        const float* p0 = isA ? (x    + (size_t)row * 256) : (Wa + (size_t)row * 256);
        const float* p1 = isA ? (iv   + (size_t)row * 64)  : (Wi + (size_t)row * 64);
        const float* p2 = isA ? (temb + (size_t)(row & 127) * 64) : (Wt + (size_t)row * 64);
        const float* src = (kk < 256) ? (p0 + kk) : ((kk < 320) ? (p1 + kk - 256) : (p2 + kk - 320));
        f[c][0] = ((const float4*)src)[0];
        f[c][1] = ((const float4*)src)[1];
    }
    #pragma unroll
    for (int c = 0; c < REPACK_NB; ++c) {
        const int idx = tid0 + c * stride;
        u16x8 o;
        o[0] = f2bf(f[c][0].x); o[1] = f2bf(f[c][0].y); o[2] = f2bf(f[c][0].z); o[3] = f2bf(f[c][0].w);
        o[4] = f2bf(f[c][1].x); o[5] = f2bf(f[c][1].y); o[6] = f2bf(f[c][1].z); o[7] = f2bf(f[c][1].w);
        *(u16x8*)(Abf + (size_t)idx * 8) = o;
    }
}

// ---------------- tproj: tp3T[4096][128], tp2T[1024][128], tp1T[256][128] (t contiguous) ----
__global__ __launch_bounds__(256) void tproj(
        const float* __restrict__ temb,
        const float* __restrict__ tW3, const float* __restrict__ tb3,
        const float* __restrict__ tW2, const float* __restrict__ tb2,
        const float* __restrict__ tW1, const float* __restrict__ tb1,
        float* __restrict__ tp3T, float* __restrict__ tp2T, float* __restrict__ tp1T) {
    __shared__ float se[32 * 64];
    const int tid = threadIdx.x;
    const int tbase = blockIdx.y * 32;
    for (int i = tid; i < 32 * 64; i += 256) se[i] = temb[tbase * 64 + i];
    __syncthreads();
    const int j = blockIdx.x * 64 + (tid >> 2);
    const float* W; const float* bias; float* outp; int jl;
    if      (j < 4096) { W = tW3; bias = tb3; outp = tp3T; jl = j; }
    else if (j < 5120) { W = tW2; bias = tb2; outp = tp2T; jl = j - 4096; }
    else               { W = tW1; bias = tb1; outp = tp1T; jl = j - 5120; }
    float4 wreg[16];
    const float4* wrow = (const float4*)(W + (size_t)jl * 64);
    #pragma unroll
    for (int k = 0; k < 16; ++k) wreg[k] = wrow[k];
    const float b = bias[jl];
    #pragma unroll
    for (int s = 0; s < 8; ++s) {
        const int tl = (tid & 3) + s * 4;
        const float4* e4 = (const float4*)&se[tl * 64];
        float a = b;
        #pragma unroll
        for (int k = 0; k < 16; ++k) {
            float4 e = e4[k];
            a += wreg[k].x * e.x + wreg[k].y * e.y + wreg[k].z * e.z + wreg[k].w * e.w;
        }
        outp[(size_t)jl * 128 + tbase + tl] = a;
    }
}

// ---------------- main: transposed GEMM (M=16384 nodes, N=2048 bt, K=384) + tree ----------------
// BK=32 (16 KB LDS -> ~4 blocks/CU), 4-chunk XOR swizzle (kchunk = c ^ (row&3)):
// staging keeps 64B-contiguous per 4 lanes, fragment ds_read_b128 spreads uniformly
// over banks (0 conflicts). Epilogue params hoisted ABOVE the K-loop so their
// latency hides under the GEMM.
// C[node][m]: per wave, 64 M-rows = 64 leaves of ONE n; leaf = i*16 + quad*4 + r
__global__ __launch_bounds__(256, 4)
void fused_gemm_tree(const unsigned short* __restrict__ Wbf,   // A-operand [16384][384]
                     const unsigned short* __restrict__ Abf,   // B-operand [2048][384]
                     const float* __restrict__ ba,
                     const float* __restrict__ tp3T, const float* __restrict__ tp2T,
                     const float* __restrict__ tp1T,
                     const float* __restrict__ w3, const float* __restrict__ w2,
                     const float* __restrict__ w1,
                     float* __restrict__ out) {
    __shared__ unsigned short sW[128 * 32];   // 8 KB
    __shared__ unsigned short sA[128 * 32];   // 8 KB

    const int tid  = threadIdx.x;
    const int wave = tid >> 6;
    const int lane = tid & 63;
    const int wr = wave >> 1;          // node half: n = blockIdx.x*2 + wr
    const int wc = wave & 1;           // time half
    const int lane15 = lane & 15;
    const int quad = lane >> 4;

    const int node0 = blockIdx.x * 128;
    const int m0    = blockIdx.y * 128;
    const int n     = blockIdx.x * 2 + wr;
    const int tbase = wc * 64 + lane15;

    // ---- hoisted epilogue parameters (latency hidden under GEMM) ----
    float bav[4][4], w3v[4][4], w2v[4], w1v[4], tp3v[4][4], tp2v[4][4], tp1v[4];
    #pragma unroll
    for (int i = 0; i < 4; ++i) {
        const float* tp3row = tp3T + (size_t)(n * 16 + i * 4 + quad) * 128;
        const float* tp2row = tp2T + (size_t)(n * 4 + i) * 128;
        #pragma unroll
        for (int r = 0; r < 4; ++r) {
            const int nl = i * 16 + quad * 4 + r;
            bav[i][r] = ba[node0 + wr * 64 + nl];
            w3v[i][r] = w3[n * 64 + nl];
        }
        #pragma unroll
        for (int j = 0; j < 4; ++j) {
            tp3v[i][j] = tp3row[tbase + j * 16];
            tp2v[i][j] = tp2row[tbase + j * 16];
        }
        w2v[i] = w2[n * 16 + i * 4 + quad];
        w1v[i] = w1[n * 4 + i];
        tp1v[i] = tp1T[(size_t)n * 128 + tbase + i * 16];
    }

    f32x4 acc[4][4];
    const f32x4 zero = {0.0f, 0.0f, 0.0f, 0.0f};
    #pragma unroll
    for (int i = 0; i < 4; ++i)
        #pragma unroll
        for (int j = 0; j < 4; ++j) acc[i][j] = zero;

    const int wrow = wr * 64 + lane15;     // A-side (node) frag row
    const int arow = wc * 64 + lane15;     // B-side (time) frag row
    const int swz  = lane15 & 3;           // read-side swizzle (row&3 of frag row)

    const unsigned short* aBase = Wbf + (size_t)node0 * 384;
    const unsigned short* bBase = Abf + (size_t)m0 * 384;

    for (int k0 = 0; k0 < 384; k0 += 32) {
        __syncthreads();
        #pragma unroll
        for (int rr = 0; rr < 2; ++rr) {
            const int p = rr * 256 + tid;              // chunk 0..511 (row = p>>2, c = p&3)
            const int row = p >> 2;
            const int kchunk = (p & 3) ^ (row & 3);    // XOR swizzle
            const size_t soff = (size_t)row * 384 + k0 + kchunk * 8;
            load16_to_lds(aBase + soff, &sW[(size_t)(rr * 256 + wave * 64) * 8]);
            load16_to_lds(bBase + soff, &sA[(size_t)(rr * 256 + wave * 64) * 8]);
        }
        __syncthreads();

        const int cpos = (quad ^ swz) * 8;
        bf16x8 af[4], bfr[4];
        #pragma unroll
        for (int i = 0; i < 4; ++i) af[i]  = *(const bf16x8*)&sW[(wrow + i * 16) * 32 + cpos];
        #pragma unroll
        for (int j = 0; j < 4; ++j) bfr[j] = *(const bf16x8*)&sA[(arow + j * 16) * 32 + cpos];
        #pragma unroll
        for (int i = 0; i < 4; ++i)
            #pragma unroll
            for (int j = 0; j < 4; ++j)
                acc[i][j] = __builtin_amdgcn_mfma_f32_16x16x32_bf16(af[i], bfr[j], acc[i][j], 0, 0, 0);
    }

    // ---- epilogue: softplus + 4/4/4 tree; l in-register, jj across quads, i in frags ----
    float s1[4] = {0.0f, 0.0f, 0.0f, 0.0f};
    #pragma unroll
    for (int i = 0; i < 4; ++i) {
        #pragma unroll
        for (int j = 0; j < 4; ++j) {
            float p3 = 0.0f;
            #pragma unroll
            for (int r = 0; r < 4; ++r) {
                float a0 = softplus_f(acc[i][j][r] + bav[i][r]);
                p3 = fmaf(a0, w3v[i][r], p3);
            }
            float a3 = softplus_f(p3 + tp3v[i][j]);
            float c2 = a3 * w2v[i];
            c2 += __shfl_xor(c2, 16);
            c2 += __shfl_xor(c2, 32);
            float a2 = softplus_f(c2 + tp2v[i][j]);
            s1[j] = fmaf(a2, w1v[i], s1[j]);
        }
    }
    // s1[j] is quad-uniform after the jj-reduction: quad q stores j=q (all lanes active)
    {
        const int j = quad;
        float sj = s1[0];
        sj = (j == 1) ? s1[1] : sj;
        sj = (j == 2) ? s1[2] : sj;
        sj = (j == 3) ? s1[3] : sj;
        float tq = tp1v[0];
        tq = (j == 1) ? tp1v[1] : tq;
        tq = (j == 2) ? tp1v[2] : tq;
        tq = (j == 3) ? tp1v[3] : tq;
        const int t = tbase + j * 16;
        out[(size_t)(m0 + t) * 256 + n] = softplus_f(sj + tq);
    }
}

// ---------------- launcher ----------------
extern "C" void kernel_launch(void* const* d_in, const int* in_sizes, int n_in,
                              void* d_out, int out_size, void* d_ws, size_t ws_size,
                              hipStream_t stream) {
    const float* x    = (const float*)d_in[0];
    const float* temb = (const float*)d_in[1];
    const float* iv   = (const float*)d_in[2];
    const float* Wa   = (const float*)d_in[3];
    const float* ba   = (const float*)d_in[4];
    const float* Wt   = (const float*)d_in[5];
    const float* Wi   = (const float*)d_in[6];
    const float* w3   = (const float*)d_in[7];
    const float* tW3  = (const float*)d_in[8];
    const float* tb3  = (const float*)d_in[9];
    const float* w2   = (const float*)d_in[10];
    const float* tW2  = (const float*)d_in[11];
    const float* tb2  = (const float*)d_in[12];
    const float* w1   = (const float*)d_in[13];
    const float* tW1  = (const float*)d_in[14];
    const float* tb1  = (const float*)d_in[15];
    float* out = (float*)d_out;

    char* ws = (char*)d_ws;
    unsigned short* Abf = (unsigned short*)(ws);              //  [2048][384] bf16
    unsigned short* Wbf = (unsigned short*)(ws + 1572864);    //  [16384][384] bf16 (contiguous after Abf)
    float* tp3T = (float*)(ws + 14155776);                    //  [4096][128]
    float* tp2T = (float*)(ws + 16252928);                    //  [1024][128]
    float* tp1T = (float*)(ws + 16777216);                    //  [256][128]

    repack<<<dim3(REPACK_BLOCKS), dim3(256), 0, stream>>>(x, iv, temb, Wa, Wi, Wt, Abf);
    tproj<<<dim3(84, 4), dim3(256), 0, stream>>>(temb, tW3, tb3, tW2, tb2, tW1, tb1,
                                                 tp3T, tp2T, tp1T);
    fused_gemm_tree<<<dim3(128, 16), dim3(256), 0, stream>>>(Wbf, Abf, ba, tp3T, tp2T, tp1T,
                                                             w3, w2, w1, out);
}

// Round 6
// 158.706 us; speedup vs baseline: 1.2364x; 1.2364x over previous
//
#include <hip/hip_runtime.h>

// ---------------- types / helpers ----------------
typedef __attribute__((ext_vector_type(4))) float f32x4;
typedef __attribute__((ext_vector_type(8))) __bf16 bf16x8;
typedef __attribute__((ext_vector_type(8))) unsigned short u16x8;

__device__ __forceinline__ unsigned short f2bf(float f) {
    unsigned int u = __float_as_uint(f);
    u += 0x7fffu + ((u >> 16) & 1u);       // RTNE
    return (unsigned short)(u >> 16);
}

__device__ __forceinline__ float softplus_f(float x) {
    float e = __expf(-fabsf(x));
    return fmaxf(x, 0.0f) + __logf(1.0f + e);
}

typedef __attribute__((address_space(3))) void lds_void_t;
typedef __attribute__((address_space(1))) void glb_void_t;

__device__ __forceinline__ void load16_to_lds(const void* g, const void* l) {
    __builtin_amdgcn_global_load_lds((glb_void_t*)(unsigned long long)g,
                                     (lds_void_t*)(unsigned int)(unsigned long long)l,
                                     16, 0, 0);
}

// ---------------- repack: bf16 A=[x|iv|temb] then W=[Wa|Wi|Wt], dst contiguous ----------------
#define REPACK_NB 4
#define REPACK_BLOCKS 864
__global__ __launch_bounds__(256) void repack(
        const float* __restrict__ x, const float* __restrict__ iv,
        const float* __restrict__ temb,
        const float* __restrict__ Wa, const float* __restrict__ Wi,
        const float* __restrict__ Wt,
        unsigned short* __restrict__ Abf /* Wbf follows contiguously */) {
    const int stride = REPACK_BLOCKS * 256;
    const int tid0 = blockIdx.x * 256 + threadIdx.x;
    float4 f[REPACK_NB][2];
    #pragma unroll
    for (int c = 0; c < REPACK_NB; ++c) {
        const int idx = tid0 + c * stride;
        const bool isA = idx < 98304;
        const int widx = isA ? idx : idx - 98304;
        const int row = widx / 48;
        const int kk  = (widx % 48) * 8;
        const float* p0 = isA ? (x    + (size_t)row * 256) : (Wa + (size_t)row * 256);
        const float* p1 = isA ? (iv   + (size_t)row * 64)  : (Wi + (size_t)row * 64);
        const float* p2 = isA ? (temb + (size_t)(row & 127) * 64) : (Wt + (size_t)row * 64);
        const float* src = (kk < 256) ? (p0 + kk) : ((kk < 320) ? (p1 + kk - 256) : (p2 + kk - 320));
        f[c][0] = ((const float4*)src)[0];
        f[c][1] = ((const float4*)src)[1];
    }
    #pragma unroll
    for (int c = 0; c < REPACK_NB; ++c) {
        const int idx = tid0 + c * stride;
        u16x8 o;
        o[0] = f2bf(f[c][0].x); o[1] = f2bf(f[c][0].y); o[2] = f2bf(f[c][0].z); o[3] = f2bf(f[c][0].w);
        o[4] = f2bf(f[c][1].x); o[5] = f2bf(f[c][1].y); o[6] = f2bf(f[c][1].z); o[7] = f2bf(f[c][1].w);
        *(u16x8*)(Abf + (size_t)idx * 8) = o;
    }
}

// ---------------- tproj: tp3T[4096][128], tp2T[1024][128], tp1T[256][128] (t contiguous) ----
__global__ __launch_bounds__(256) void tproj(
        const float* __restrict__ temb,
        const float* __restrict__ tW3, const float* __restrict__ tb3,
        const float* __restrict__ tW2, const float* __restrict__ tb2,
        const float* __restrict__ tW1, const float* __restrict__ tb1,
        float* __restrict__ tp3T, float* __restrict__ tp2T, float* __restrict__ tp1T) {
    __shared__ float se[32 * 64];
    const int tid = threadIdx.x;
    const int tbase = blockIdx.y * 32;
    for (int i = tid; i < 32 * 64; i += 256) se[i] = temb[tbase * 64 + i];
    __syncthreads();
    const int j = blockIdx.x * 64 + (tid >> 2);
    const float* W; const float* bias; float* outp; int jl;
    if      (j < 4096) { W = tW3; bias = tb3; outp = tp3T; jl = j; }
    else if (j < 5120) { W = tW2; bias = tb2; outp = tp2T; jl = j - 4096; }
    else               { W = tW1; bias = tb1; outp = tp1T; jl = j - 5120; }
    float4 wreg[16];
    const float4* wrow = (const float4*)(W + (size_t)jl * 64);
    #pragma unroll
    for (int k = 0; k < 16; ++k) wreg[k] = wrow[k];
    const float b = bias[jl];
    #pragma unroll
    for (int s = 0; s < 8; ++s) {
        const int tl = (tid & 3) + s * 4;
        const float4* e4 = (const float4*)&se[tl * 64];
        float a = b;
        #pragma unroll
        for (int k = 0; k < 16; ++k) {
            float4 e = e4[k];
            a += wreg[k].x * e.x + wreg[k].y * e.y + wreg[k].z * e.z + wreg[k].w * e.w;
        }
        outp[(size_t)jl * 128 + tbase + tl] = a;
    }
}

// ---------------- main: transposed GEMM (M=16384 nodes, N=2048 bt, K=384) + tree ----------------
// BK=64, XOR-8 swizzle (kchunk = c ^ (row&7)): 128B rows -> frag ds_read_b128 covers
// all 32 banks, 0 conflicts (verified R4). launch_bounds(256,3) gives the allocator
// ~170 regs/thread so 64 AGPR acc + temporaries fit WITHOUT scratch spill (R4's 128-reg
// cap caused ~60MB of spill write traffic).
// C[node][m]: per wave, 64 M-rows = 64 leaves of ONE n; leaf = i*16 + quad*4 + r
__global__ __launch_bounds__(256, 3)
void fused_gemm_tree(const unsigned short* __restrict__ Wbf,   // A-operand [16384][384]
                     const unsigned short* __restrict__ Abf,   // B-operand [2048][384]
                     const float* __restrict__ ba,
                     const float* __restrict__ tp3T, const float* __restrict__ tp2T,
                     const float* __restrict__ tp1T,
                     const float* __restrict__ w3, const float* __restrict__ w2,
                     const float* __restrict__ w1,
                     float* __restrict__ out) {
    __shared__ unsigned short sW[128 * 64];   // 16 KB
    __shared__ unsigned short sA[128 * 64];   // 16 KB

    const int tid  = threadIdx.x;
    const int wave = tid >> 6;
    const int lane = tid & 63;
    const int wr = wave >> 1;          // node half: n = blockIdx.x*2 + wr
    const int wc = wave & 1;           // time half
    const int lane15 = lane & 15;
    const int quad = lane >> 4;

    const int node0 = blockIdx.x * 128;
    const int m0    = blockIdx.y * 128;

    f32x4 acc[4][4];
    const f32x4 zero = {0.0f, 0.0f, 0.0f, 0.0f};
    #pragma unroll
    for (int i = 0; i < 4; ++i)
        #pragma unroll
        for (int j = 0; j < 4; ++j) acc[i][j] = zero;

    const int wrow = wr * 64 + lane15;     // A-side (node) frag row
    const int arow = wc * 64 + lane15;     // B-side (time) frag row
    const int swz  = lane15 & 7;           // read-side swizzle (row&7 of frag row)

    const unsigned short* aBase = Wbf + (size_t)node0 * 384;
    const unsigned short* bBase = Abf + (size_t)m0 * 384;

    for (int k0 = 0; k0 < 384; k0 += 64) {
        __syncthreads();
        #pragma unroll
        for (int rr = 0; rr < 4; ++rr) {
            const int p = rr * 256 + tid;              // chunk 0..1023 (row = p>>3, c = p&7)
            const int row = p >> 3;
            const int kchunk = (p & 7) ^ (row & 7);    // XOR swizzle
            const size_t soff = (size_t)row * 384 + k0 + kchunk * 8;
            load16_to_lds(aBase + soff, &sW[(size_t)(rr * 256 + wave * 64) * 8]);
            load16_to_lds(bBase + soff, &sA[(size_t)(rr * 256 + wave * 64) * 8]);
        }
        __syncthreads();

        #pragma unroll
        for (int s = 0; s < 2; ++s) {
            const int cpos = ((s * 4 + quad) ^ swz) * 8;
            bf16x8 af[4], bfr[4];
            #pragma unroll
            for (int i = 0; i < 4; ++i) af[i]  = *(const bf16x8*)&sW[(wrow + i * 16) * 64 + cpos];
            #pragma unroll
            for (int j = 0; j < 4; ++j) bfr[j] = *(const bf16x8*)&sA[(arow + j * 16) * 64 + cpos];
            #pragma unroll
            for (int i = 0; i < 4; ++i)
                #pragma unroll
                for (int j = 0; j < 4; ++j)
                    acc[i][j] = __builtin_amdgcn_mfma_f32_16x16x32_bf16(af[i], bfr[j], acc[i][j], 0, 0, 0);
        }
    }

    // ---- epilogue: softplus + 4/4/4 tree; l in-register, jj across quads, i in frags ----
    const int n = blockIdx.x * 2 + wr;

    float bav[4][4], w3v[4][4], w2v[4], w1v[4];
    #pragma unroll
    for (int i = 0; i < 4; ++i) {
        #pragma unroll
        for (int r = 0; r < 4; ++r) {
            const int nl = i * 16 + quad * 4 + r;
            bav[i][r] = ba[node0 + wr * 64 + nl];
            w3v[i][r] = w3[n * 64 + nl];
        }
        w2v[i] = w2[n * 16 + i * 4 + quad];
        w1v[i] = w1[n * 4 + i];
    }

    const int tbase = wc * 64 + lane15;
    float s1[4] = {0.0f, 0.0f, 0.0f, 0.0f};

    #pragma unroll
    for (int i = 0; i < 4; ++i) {
        const float* tp3row = tp3T + (size_t)(n * 16 + i * 4 + quad) * 128;
        const float* tp2row = tp2T + (size_t)(n * 4 + i) * 128;
        #pragma unroll
        for (int j = 0; j < 4; ++j) {
            const int t = tbase + j * 16;
            float p3 = 0.0f;
            #pragma unroll
            for (int r = 0; r < 4; ++r) {
                float a0 = softplus_f(acc[i][j][r] + bav[i][r]);
                p3 = fmaf(a0, w3v[i][r], p3);
            }
            float a3 = softplus_f(p3 + tp3row[t]);
            float c2 = a3 * w2v[i];
            c2 += __shfl_xor(c2, 16);
            c2 += __shfl_xor(c2, 32);
            float a2 = softplus_f(c2 + tp2row[t]);
            s1[j] = fmaf(a2, w1v[i], s1[j]);
        }
    }
    #pragma unroll
    for (int j = 0; j < 4; ++j) {
        const int t = tbase + j * 16;
        float o = softplus_f(s1[j] + tp1T[(size_t)n * 128 + t]);
        if (quad == 0) out[(size_t)(m0 + t) * 256 + n] = o;
    }
}

// ---------------- launcher ----------------
extern "C" void kernel_launch(void* const* d_in, const int* in_sizes, int n_in,
                              void* d_out, int out_size, void* d_ws, size_t ws_size,
                              hipStream_t stream) {
    const float* x    = (const float*)d_in[0];
    const float* temb = (const float*)d_in[1];
    const float* iv   = (const float*)d_in[2];
    const float* Wa   = (const float*)d_in[3];
    const float* ba   = (const float*)d_in[4];
    const float* Wt   = (const float*)d_in[5];
    const float* Wi   = (const float*)d_in[6];
    const float* w3   = (const float*)d_in[7];
    const float* tW3  = (const float*)d_in[8];
    const float* tb3  = (const float*)d_in[9];
    const float* w2   = (const float*)d_in[10];
    const float* tW2  = (const float*)d_in[11];
    const float* tb2  = (const float*)d_in[12];
    const float* w1   = (const float*)d_in[13];
    const float* tW1  = (const float*)d_in[14];
    const float* tb1  = (const float*)d_in[15];
    float* out = (float*)d_out;

    char* ws = (char*)d_ws;
    unsigned short* Abf = (unsigned short*)(ws);              //  [2048][384] bf16
    unsigned short* Wbf = (unsigned short*)(ws + 1572864);    //  [16384][384] bf16 (contiguous after Abf)
    float* tp3T = (float*)(ws + 14155776);                    //  [4096][128]
    float* tp2T = (float*)(ws + 16252928);                    //  [1024][128]
    float* tp1T = (float*)(ws + 16777216);                    //  [256][128]

    repack<<<dim3(REPACK_BLOCKS), dim3(256), 0, stream>>>(x, iv, temb, Wa, Wi, Wt, Abf);
    tproj<<<dim3(84, 4), dim3(256), 0, stream>>>(temb, tW3, tb3, tW2, tb2, tW1, tb1,
                                                 tp3T, tp2T, tp1T);
    fused_gemm_tree<<<dim3(128, 16), dim3(256), 0, stream>>>(Wbf, Abf, ba, tp3T, tp2T, tp1T,
                                                             w3, w2, w1, out);
}

// Round 7
// 155.770 us; speedup vs baseline: 1.2597x; 1.0188x over previous
//
#include <hip/hip_runtime.h>

// ---------------- types / helpers ----------------
typedef __attribute__((ext_vector_type(16))) float f32x16;
typedef __attribute__((ext_vector_type(8))) __bf16 bf16x8;
typedef __attribute__((ext_vector_type(8))) unsigned short u16x8;

__device__ __forceinline__ unsigned short f2bf(float f) {
    unsigned int u = __float_as_uint(f);
    u += 0x7fffu + ((u >> 16) & 1u);       // RTNE
    return (unsigned short)(u >> 16);
}

__device__ __forceinline__ float softplus_f(float x) {
    float e = __expf(-fabsf(x));
    return fmaxf(x, 0.0f) + __logf(1.0f + e);
}

typedef __attribute__((address_space(3))) void lds_void_t;
typedef __attribute__((address_space(1))) void glb_void_t;

__device__ __forceinline__ void load16_to_lds(const void* g, const void* l) {
    __builtin_amdgcn_global_load_lds((glb_void_t*)(unsigned long long)g,
                                     (lds_void_t*)(unsigned int)(unsigned long long)l,
                                     16, 0, 0);
}

// ---------------- repack: bf16 A=[x|iv|temb] then W=[Wa|Wi|Wt], dst contiguous ----------------
#define REPACK_NB 2
#define REPACK_BLOCKS 1728
__global__ __launch_bounds__(256) void repack(
        const float* __restrict__ x, const float* __restrict__ iv,
        const float* __restrict__ temb,
        const float* __restrict__ Wa, const float* __restrict__ Wi,
        const float* __restrict__ Wt,
        unsigned short* __restrict__ Abf /* Wbf follows contiguously */) {
    const int stride = REPACK_BLOCKS * 256;
    const int tid0 = blockIdx.x * 256 + threadIdx.x;
    float4 f[REPACK_NB][2];
    #pragma unroll
    for (int c = 0; c < REPACK_NB; ++c) {
        const int idx = tid0 + c * stride;
        const bool isA = idx < 98304;
        const int widx = isA ? idx : idx - 98304;
        const int row = widx / 48;
        const int kk  = (widx % 48) * 8;
        const float* p0 = isA ? (x    + (size_t)row * 256) : (Wa + (size_t)row * 256);
        const float* p1 = isA ? (iv   + (size_t)row * 64)  : (Wi + (size_t)row * 64);
        const float* p2 = isA ? (temb + (size_t)(row & 127) * 64) : (Wt + (size_t)row * 64);
        const float* src = (kk < 256) ? (p0 + kk) : ((kk < 320) ? (p1 + kk - 256) : (p2 + kk - 320));
        f[c][0] = ((const float4*)src)[0];
        f[c][1] = ((const float4*)src)[1];
    }
    #pragma unroll
    for (int c = 0; c < REPACK_NB; ++c) {
        const int idx = tid0 + c * stride;
        u16x8 o;
        o[0] = f2bf(f[c][0].x); o[1] = f2bf(f[c][0].y); o[2] = f2bf(f[c][0].z); o[3] = f2bf(f[c][0].w);
        o[4] = f2bf(f[c][1].x); o[5] = f2bf(f[c][1].y); o[6] = f2bf(f[c][1].z); o[7] = f2bf(f[c][1].w);
        *(u16x8*)(Abf + (size_t)idx * 8) = o;
    }
}

// ---------------- tproj: tp3T[4096][128], tp2T[1024][128], tp1T[256][128] (t contiguous) ----
__global__ __launch_bounds__(256) void tproj(
        const float* __restrict__ temb,
        const float* __restrict__ tW3, const float* __restrict__ tb3,
        const float* __restrict__ tW2, const float* __restrict__ tb2,
        const float* __restrict__ tW1, const float* __restrict__ tb1,
        float* __restrict__ tp3T, float* __restrict__ tp2T, float* __restrict__ tp1T) {
    __shared__ float se[32 * 64];
    const int tid = threadIdx.x;
    const int tbase = blockIdx.y * 32;
    for (int i = tid; i < 32 * 64; i += 256) se[i] = temb[tbase * 64 + i];
    __syncthreads();
    const int j = blockIdx.x * 64 + (tid >> 2);
    const float* W; const float* bias; float* outp; int jl;
    if      (j < 4096) { W = tW3; bias = tb3; outp = tp3T; jl = j; }
    else if (j < 5120) { W = tW2; bias = tb2; outp = tp2T; jl = j - 4096; }
    else               { W = tW1; bias = tb1; outp = tp1T; jl = j - 5120; }
    float4 wreg[16];
    const float4* wrow = (const float4*)(W + (size_t)jl * 64);
    #pragma unroll
    for (int k = 0; k < 16; ++k) wreg[k] = wrow[k];
    const float b = bias[jl];
    #pragma unroll
    for (int s = 0; s < 8; ++s) {
        const int tl = (tid & 3) + s * 4;
        const float4* e4 = (const float4*)&se[tl * 64];
        float a = b;
        #pragma unroll
        for (int k = 0; k < 16; ++k) {
            float4 e = e4[k];
            a += wreg[k].x * e.x + wreg[k].y * e.y + wreg[k].z * e.z + wreg[k].w * e.w;
        }
        outp[(size_t)jl * 128 + tbase + tl] = a;
    }
}

// ---------------- main: transposed GEMM (M=16384 nodes, N=2048 bt, K=384) + tree ----------------
// 32x32x16 MFMA. BK=64, XOR-8 swizzle (chunk stored at c^(row&7)) identical to R6.
// C-layout (m74/m101): col = lane&31 (time), row = (reg&3) + 8*(reg>>2) + 4*(lane>>5).
// Wave = 64 node-rows (leaves of ONE n) x 64 t; frags fm (node half) x cf (time half).
// leaf = fm*32 + 8*s2 + 4*h + l  (l=reg&3 in-reg, s2=reg>>2 in-reg, h=lane>>5)
//   -> l in-register; jj = 2*(s2&1)+h (1 shuffle); i = fm*2 + (s2>>1) in-register.
__global__ __launch_bounds__(256, 3)
void fused_gemm_tree(const unsigned short* __restrict__ Wbf,   // A-operand [16384][384]
                     const unsigned short* __restrict__ Abf,   // B-operand [2048][384]
                     const float* __restrict__ ba,
                     const float* __restrict__ tp3T, const float* __restrict__ tp2T,
                     const float* __restrict__ tp1T,
                     const float* __restrict__ w3, const float* __restrict__ w2,
                     const float* __restrict__ w1,
                     float* __restrict__ out) {
    __shared__ unsigned short sW[128 * 64];   // 16 KB
    __shared__ unsigned short sA[128 * 64];   // 16 KB

    const int tid  = threadIdx.x;
    const int wave = tid >> 6;
    const int lane = tid & 63;
    const int wr = wave >> 1;          // node half: n = blockIdx.x*2 + wr
    const int wc = wave & 1;           // time half
    const int lane31 = lane & 31;
    const int h = lane >> 5;

    const int node0 = blockIdx.x * 128;
    const int m0    = blockIdx.y * 128;

    f32x16 acc[2][2];
    #pragma unroll
    for (int fm = 0; fm < 2; ++fm)
        #pragma unroll
        for (int cf = 0; cf < 2; ++cf)
            #pragma unroll
            for (int r = 0; r < 16; ++r) acc[fm][cf][r] = 0.0f;

    const unsigned short* aBase = Wbf + (size_t)node0 * 384;
    const unsigned short* bBase = Abf + (size_t)m0 * 384;

    // fragment rows (per fm/cf) and the lane's k-chunk half
    const int wrow0 = wr * 64 + lane31;        // + fm*32
    const int arow0 = wc * 64 + lane31;        // + cf*32

    for (int k0 = 0; k0 < 384; k0 += 64) {
        __syncthreads();
        #pragma unroll
        for (int rr = 0; rr < 4; ++rr) {
            const int p = rr * 256 + tid;              // chunk 0..1023 (row = p>>3, c = p&7)
            const int row = p >> 3;
            const int kchunk = (p & 7) ^ (row & 7);    // XOR swizzle
            const size_t soff = (size_t)row * 384 + k0 + kchunk * 8;
            load16_to_lds(aBase + soff, &sW[(size_t)(rr * 256 + wave * 64) * 8]);
            load16_to_lds(bBase + soff, &sA[(size_t)(rr * 256 + wave * 64) * 8]);
        }
        __syncthreads();

        #pragma unroll
        for (int s = 0; s < 4; ++s) {                  // K=16 per step
            const int kc = s * 2 + h;                  // lane's 8-elem chunk index
            bf16x8 af[2], bf[2];
            #pragma unroll
            for (int fm = 0; fm < 2; ++fm) {
                const int row = wrow0 + fm * 32;
                af[fm] = *(const bf16x8*)&sW[row * 64 + (kc ^ (row & 7)) * 8];
            }
            #pragma unroll
            for (int cf = 0; cf < 2; ++cf) {
                const int row = arow0 + cf * 32;
                bf[cf] = *(const bf16x8*)&sA[row * 64 + (kc ^ (row & 7)) * 8];
            }
            #pragma unroll
            for (int fm = 0; fm < 2; ++fm)
                #pragma unroll
                for (int cf = 0; cf < 2; ++cf)
                    acc[fm][cf] = __builtin_amdgcn_mfma_f32_32x32x16_bf16(af[fm], bf[cf], acc[fm][cf], 0, 0, 0);
        }
    }

    // ---- epilogue: softplus + 4/4/4 tree ----
    const int n = blockIdx.x * 2 + wr;
    const int t0 = wc * 64 + lane31;                   // + cf*32 -> t

    // parameter loads (l contiguous -> float4 for ba/w3)
    float4 bav[2][4], w3v[2][4];
    #pragma unroll
    for (int fm = 0; fm < 2; ++fm)
        #pragma unroll
        for (int s2 = 0; s2 < 4; ++s2) {
            const int leafbase = fm * 32 + 8 * s2 + 4 * h;
            bav[fm][s2] = *(const float4*)&ba[node0 + wr * 64 + leafbase];
            w3v[fm][s2] = *(const float4*)&w3[n * 64 + leafbase];
        }
    float w2v[4][2], w1v[4];                            // [i][s2b] , jj = 2*s2b + h
    #pragma unroll
    for (int i = 0; i < 4; ++i) {
        #pragma unroll
        for (int s2b = 0; s2b < 2; ++s2b)
            w2v[i][s2b] = w2[n * 16 + i * 4 + 2 * s2b + h];
        w1v[i] = w1[n * 4 + i];
    }
    float tp3v[2][2][4], tp2v[2][2][2], tp1v[2];
    #pragma unroll
    for (int fm = 0; fm < 2; ++fm)
        #pragma unroll
        for (int cf = 0; cf < 2; ++cf) {
            const int t = t0 + cf * 32;
            #pragma unroll
            for (int s2 = 0; s2 < 4; ++s2) {
                const int i  = fm * 2 + (s2 >> 1);
                const int jj = 2 * (s2 & 1) + h;
                tp3v[fm][cf][s2] = tp3T[(size_t)((n * 4 + i) * 4 + jj) * 128 + t];
            }
            #pragma unroll
            for (int b = 0; b < 2; ++b)
                tp2v[fm][cf][b] = tp2T[(size_t)(n * 4 + fm * 2 + b) * 128 + t];
        }
    #pragma unroll
    for (int cf = 0; cf < 2; ++cf) tp1v[cf] = tp1T[(size_t)n * 128 + t0 + cf * 32];

    float s1[2] = {0.0f, 0.0f};
    #pragma unroll
    for (int fm = 0; fm < 2; ++fm) {
        #pragma unroll
        for (int cf = 0; cf < 2; ++cf) {
            #pragma unroll
            for (int b = 0; b < 2; ++b) {               // i = fm*2 + b
                float cs = 0.0f;
                #pragma unroll
                for (int s2b = 0; s2b < 2; ++s2b) {
                    const int s2 = 2 * b + s2b;
                    float p3 = 0.0f;
                    const float* bv = (const float*)&bav[fm][s2];
                    const float* wv = (const float*)&w3v[fm][s2];
                    #pragma unroll
                    for (int l = 0; l < 4; ++l) {
                        float a0 = softplus_f(acc[fm][cf][s2 * 4 + l] + bv[l]);
                        p3 = fmaf(a0, wv[l], p3);
                    }
                    float a3 = softplus_f(p3 + tp3v[fm][cf][s2]);
                    cs = fmaf(a3, w2v[fm * 2 + b][s2b], cs);
                }
                float Q = cs + __shfl_xor(cs, 32);      // jj-sum across halves
                float a2 = softplus_f(Q + tp2v[fm][cf][b]);
                s1[cf] = fmaf(a2, w1v[fm * 2 + b], s1[cf]);
            }
        }
    }
    // half h stores cf = h (s1 identical in both halves): 64 unique (t, n)
    {
        const float sj = h ? s1[1] : s1[0];
        const float tq = h ? tp1v[1] : tp1v[0];
        const int t = t0 + h * 32;
        out[(size_t)(m0 + t) * 256 + n] = softplus_f(sj + tq);
    }
}

// ---------------- launcher ----------------
extern "C" void kernel_launch(void* const* d_in, const int* in_sizes, int n_in,
                              void* d_out, int out_size, void* d_ws, size_t ws_size,
                              hipStream_t stream) {
    const float* x    = (const float*)d_in[0];
    const float* temb = (const float*)d_in[1];
    const float* iv   = (const float*)d_in[2];
    const float* Wa   = (const float*)d_in[3];
    const float* ba   = (const float*)d_in[4];
    const float* Wt   = (const float*)d_in[5];
    const float* Wi   = (const float*)d_in[6];
    const float* w3   = (const float*)d_in[7];
    const float* tW3  = (const float*)d_in[8];
    const float* tb3  = (const float*)d_in[9];
    const float* w2   = (const float*)d_in[10];
    const float* tW2  = (const float*)d_in[11];
    const float* tb2  = (const float*)d_in[12];
    const float* w1   = (const float*)d_in[13];
    const float* tW1  = (const float*)d_in[14];
    const float* tb1  = (const float*)d_in[15];
    float* out = (float*)d_out;

    char* ws = (char*)d_ws;
    unsigned short* Abf = (unsigned short*)(ws);              //  [2048][384] bf16
    unsigned short* Wbf = (unsigned short*)(ws + 1572864);    //  [16384][384] bf16 (contiguous after Abf)
    float* tp3T = (float*)(ws + 14155776);                    //  [4096][128]
    float* tp2T = (float*)(ws + 16252928);                    //  [1024][128]
    float* tp1T = (float*)(ws + 16777216);                    //  [256][128]

    repack<<<dim3(REPACK_BLOCKS), dim3(256), 0, stream>>>(x, iv, temb, Wa, Wi, Wt, Abf);
    tproj<<<dim3(84, 4), dim3(256), 0, stream>>>(temb, tW3, tb3, tW2, tb2, tW1, tb1,
                                                 tp3T, tp2T, tp1T);
    fused_gemm_tree<<<dim3(128, 16), dim3(256), 0, stream>>>(Wbf, Abf, ba, tp3T, tp2T, tp1T,
                                                             w3, w2, w1, out);
}